// Round 4
// baseline (106.426 us; speedup 1.0000x reference)
//
#include <hip/hip_runtime.h>
#include <math.h>
#include <stdint.h>

#define B_ 16
#define L_ 50
#define LU_ 60
#define KU_ 100
#define DIM_ 60
#define V_ 2000
#define MAXVL_ 10
#define MIN_WL_ 4
#define MAX_WL_ 10
#define NE_ 7            // MAX_WL - MIN_WL + 1
#define IDC_ 3.5f
#define LOG_UNEXT_ (-4.6051701859880913680359829093687f)  // log(0.01)
#define CTXW_ 0.1f
#define NQ_ 13           // l-quads per batch row (13*4 >= 50)

// workspace layout (bytes)
#define WS_PLP  0                  // pos_lp(+2*IDC): B*L*KU = 80000 floats
#define WS_BEST_BYTES (80000u * 4u)       // 320000: 16 padded u64 slots
#define BEST_STRIDE 8              // 64 B between per-batch atomic slots
#define WS_VPACK_BYTES (WS_BEST_BYTES + 1024u)  // 321024 (16B aligned): 2000 int4

#define URP_ 61   // padded LDS stride (odd -> conflict-free strided reads)
#define CWP_ 61

// DP tile: pair rows (r, r+5) as float2, stride S2_ dwords.
// Lane-to-bank step = 202 mod 32 = 10 -> 64 lanes put exactly 4 dwords on
// each of the 32 banks per b64 read = minimum bank cycles (conflict-free).
#define S2_ 202
#define NKEY_ 54  // keys 0..53 (lane<=49, d<=4)

// -------------------------------------------------------------------------
// Kernel 1: fused prep+ctx (208 blocks) + vocab byte-pack (block 208, no
// sort needed anymore: dp reads vocab wave-uniformly).
// ws_plp stores pos_lp + 2*IDC (potential-transformed DP operand).
__global__ __launch_bounds__(256) void ctx_kernel(
    const int* __restrict__ uid,        // (B, L)
    const float* __restrict__ unit_repr,// (KU, DIM)
    const float* __restrict__ aligner_w,// (LU, KU)
    const float* __restrict__ conv_w,   // (DIM, DIM, 3)
    const float* __restrict__ conv_b,   // (DIM,)
    const int* __restrict__ vocab_ids,  // (V, MAXVL)
    const int* __restrict__ vocab_lengths, // (V,)
    float* __restrict__ ws_plp,         // (B*L, KU)
    float* __restrict__ out_align,      // (LU, KU)
    unsigned long long* __restrict__ g_best,
    int* __restrict__ vpack)            // (V, int4)
{
  int blk = blockIdx.x;
  int t = threadIdx.x;

  // ---- pack block: vpack[v] = {3 byte-packed id dwords, vlen | v<<8}
  if (blk == B_ * NQ_) {
    for (int v = t; v < V_; v += 256) {
      int vl = vocab_lengths[v];
      unsigned q0 = 0u, q1 = 0u, q2 = 0u;
#pragma unroll
      for (int j = 0; j < 4; ++j) q0 |= ((unsigned)vocab_ids[v * MAXVL_ + j]) << (j * 8);
#pragma unroll
      for (int j = 0; j < 4; ++j) q1 |= ((unsigned)vocab_ids[v * MAXVL_ + 4 + j]) << (j * 8);
#pragma unroll
      for (int j = 0; j < 2; ++j) q2 |= ((unsigned)vocab_ids[v * MAXVL_ + 8 + j]) << (j * 8);
      int4 w;
      w.x = (int)q0; w.y = (int)q1; w.z = (int)q2;
      w.w = (int)((unsigned)vl | ((unsigned)v << 8));
      ((int4*)vpack)[v] = w;
    }
    return;
  }

  int b = blk / NQ_, q = blk % NQ_;
  int l0 = 4 * q;
  int npos = (l0 + 4 <= L_) ? 4 : (L_ - l0);
  int alr = (blk < LU_) ? blk : -1;

  __shared__ float s_ur[KU_ * URP_];       // unit_repr padded (6100)
  __shared__ float s_cw[3 * DIM_ * CWP_];  // conv_w transposed (10980)
  __shared__ float s_aw[7 * KU_];          // 6 neighborhood aligner rows + align row
  __shared__ float s_kx[7 * DIM_];         // 6 ku rows + align ku row
  __shared__ float swr[4 * DIM_];          // conv outputs
  __shared__ float sclp[4 * KU_];          // char logits per position
  __shared__ float sctx[4 * KU_];          // ctx logits per position
  __shared__ float salg[KU_];              // align logits
  __shared__ float sls[9];                 // 8 pos logsumexps + align

  if (blk == 0 && t < B_) g_best[t * BEST_STRIDE] = 0ull;

  // --- P0: stage weights (float4 global) + aligner rows
  const float4* ur4 = (const float4*)unit_repr;
  for (int k = t; k < (KU_ * DIM_) / 4; k += 256) {
    float4 v = ur4[k];
    int i0 = 4 * k;
    s_ur[((i0 + 0) / DIM_) * URP_ + ((i0 + 0) % DIM_)] = v.x;
    s_ur[((i0 + 1) / DIM_) * URP_ + ((i0 + 1) % DIM_)] = v.y;
    s_ur[((i0 + 2) / DIM_) * URP_ + ((i0 + 2) % DIM_)] = v.z;
    s_ur[((i0 + 3) / DIM_) * URP_ + ((i0 + 3) % DIM_)] = v.w;
  }
  const float4* cw4 = (const float4*)conv_w;
  for (int k = t; k < (DIM_ * DIM_ * 3) / 4; k += 256) {
    float4 v = cw4[k];
    int i0 = 4 * k;
    float vv[4] = {v.x, v.y, v.z, v.w};
#pragma unroll
    for (int e = 0; e < 4; ++e) {
      int idx = i0 + e;
      int o = idx / (3 * DIM_), id = idx % (3 * DIM_);
      s_cw[id * CWP_ + o] = vv[e];
    }
  }
  for (int i = t; i < 7 * KU_; i += 256) {
    int m = i / KU_, k = i - m * KU_;
    float w = 0.f;
    if (m < 6) {
      int ld = l0 - 1 + m;
      if (ld >= 0 && ld < L_) {
        int u = uid[b * L_ + ld];
        w = aligner_w[u * KU_ + k];
      }
    } else if (alr >= 0) {
      w = aligner_w[alr * KU_ + k];
    }
    s_aw[i] = w;
  }
  __syncthreads();

  // --- P1: ku rows (420 outputs, 100 MACs)
  for (int idx = t; idx < 7 * DIM_; idx += 256) {
    int m = idx / DIM_, c = idx - m * DIM_;
    const float4* aw4 = (const float4*)&s_aw[m * KU_];
    float acc = 0.f;
    for (int k4 = 0; k4 < KU_ / 4; ++k4) {
      float4 a = aw4[k4];
      int k = 4 * k4;
      acc += a.x * s_ur[(k + 0) * URP_ + c];
      acc += a.y * s_ur[(k + 1) * URP_ + c];
      acc += a.z * s_ur[(k + 2) * URP_ + c];
      acc += a.w * s_ur[(k + 3) * URP_ + c];
    }
    s_kx[idx] = acc;
  }
  __syncthreads();

  // --- P2: conv (240) + char logits (400)
  for (int idx = t; idx < 240 + 4 * KU_; idx += 256) {
    if (idx < 240) {
      int p = idx / DIM_, o = idx - p * DIM_;
      const float4* x04 = (const float4*)&s_kx[(p + 0) * DIM_];
      const float4* x14 = (const float4*)&s_kx[(p + 1) * DIM_];
      const float4* x24 = (const float4*)&s_kx[(p + 2) * DIM_];
      float acc = conv_b[o];
      for (int i4 = 0; i4 < DIM_ / 4; ++i4) {
        float4 x0 = x04[i4], x1 = x14[i4], x2 = x24[i4];
        int i = 4 * i4;
        acc += x0.x * s_cw[((i + 0) * 3 + 0) * CWP_ + o];
        acc += x1.x * s_cw[((i + 0) * 3 + 1) * CWP_ + o];
        acc += x2.x * s_cw[((i + 0) * 3 + 2) * CWP_ + o];
        acc += x0.y * s_cw[((i + 1) * 3 + 0) * CWP_ + o];
        acc += x1.y * s_cw[((i + 1) * 3 + 1) * CWP_ + o];
        acc += x2.y * s_cw[((i + 1) * 3 + 2) * CWP_ + o];
        acc += x0.z * s_cw[((i + 2) * 3 + 0) * CWP_ + o];
        acc += x1.z * s_cw[((i + 2) * 3 + 1) * CWP_ + o];
        acc += x2.z * s_cw[((i + 2) * 3 + 2) * CWP_ + o];
        acc += x0.w * s_cw[((i + 3) * 3 + 0) * CWP_ + o];
        acc += x1.w * s_cw[((i + 3) * 3 + 1) * CWP_ + o];
        acc += x2.w * s_cw[((i + 3) * 3 + 2) * CWP_ + o];
      }
      swr[p * DIM_ + o] = acc;
    } else {
      int r = idx - 240;
      int p = r / KU_, j = r - p * KU_;
      const float4* kx4 = (const float4*)&s_kx[(p + 1) * DIM_];
      float acc = 0.f;
      for (int d4 = 0; d4 < DIM_ / 4; ++d4) {
        float4 x = kx4[d4];
        int d = 4 * d4;
        acc += x.x * s_ur[j * URP_ + d + 0];
        acc += x.y * s_ur[j * URP_ + d + 1];
        acc += x.z * s_ur[j * URP_ + d + 2];
        acc += x.w * s_ur[j * URP_ + d + 3];
      }
      sclp[r] = acc;
    }
  }
  __syncthreads();

  // --- P3: ctx logits (400) + align logits (100)
  for (int idx = t; idx < 4 * KU_ + KU_; idx += 256) {
    if (idx < 4 * KU_) {
      int p = idx / KU_, j = idx - p * KU_;
      const float4* w4 = (const float4*)&swr[p * DIM_];
      float acc = 0.f;
      for (int d4 = 0; d4 < DIM_ / 4; ++d4) {
        float4 x = w4[d4];
        int d = 4 * d4;
        acc += x.x * s_ur[j * URP_ + d + 0];
        acc += x.y * s_ur[j * URP_ + d + 1];
        acc += x.z * s_ur[j * URP_ + d + 2];
        acc += x.w * s_ur[j * URP_ + d + 3];
      }
      sctx[idx] = acc;
    } else {
      int j = idx - 4 * KU_;
      const float4* kx4 = (const float4*)&s_kx[6 * DIM_];
      float acc = 0.f;
      for (int d4 = 0; d4 < DIM_ / 4; ++d4) {
        float4 x = kx4[d4];
        int d = 4 * d4;
        acc += x.x * s_ur[j * URP_ + d + 0];
        acc += x.y * s_ur[j * URP_ + d + 1];
        acc += x.z * s_ur[j * URP_ + d + 2];
        acc += x.w * s_ur[j * URP_ + d + 3];
      }
      salg[j] = acc;
    }
  }
  __syncthreads();

  // --- P4: 9 logsumexp reductions
  {
    int g = t >> 5, lane = t & 31;
#pragma unroll
    for (int round = 0; round < 2; ++round) {
      int r = round * 8 + g;
      if (r < 9) {
        const float* arr = (r == 8) ? salg
                          : ((r & 1) ? &sctx[(r >> 1) * KU_] : &sclp[(r >> 1) * KU_]);
        float v1 = arr[lane];
        float v2 = arr[32 + lane];
        float v3 = arr[64 + lane];
        float v4 = (lane < KU_ - 96) ? arr[96 + lane] : -1e30f;
        float mx = fmaxf(fmaxf(v1, v2), fmaxf(v3, v4));
#pragma unroll
        for (int off = 16; off > 0; off >>= 1)
          mx = fmaxf(mx, __shfl_xor(mx, off));
        float s = expf(v1 - mx) + expf(v2 - mx) + expf(v3 - mx) +
                  ((lane < KU_ - 96) ? expf(v4 - mx) : 0.f);
#pragma unroll
        for (int off = 16; off > 0; off >>= 1)
          s += __shfl_xor(s, off);
        if (lane == 0) sls[r] = mx + logf(s);
      }
    }
  }
  __syncthreads();

  // --- P5: guarded outputs (pos_lp + 2*IDC: DP potential-transform operand)
  for (int idx = t; idx < 4 * KU_; idx += 256) {
    int p = idx / KU_, j = idx - p * KU_;
    if (p < npos) {
      float pos = (sclp[idx] - sls[2 * p]) + CTXW_ * (sctx[idx] - sls[2 * p + 1]);
      ws_plp[(b * L_ + l0 + p) * KU_ + j] = pos + 2.0f * IDC_;
    }
  }
  if (alr >= 0 && t < KU_)
    out_align[alr * KU_ + t] = expf(salg[t] - sls[8]);
}

// -------------------------------------------------------------------------
// DP core for one wave-uniform vocab of length VL.
// Potential transform: D[i][j] = max3(D[i-1][j-1] + s2, D[i-1][j], D[i][j-1]),
// zero boundaries; s2 = plp + 2*IDC (pre-baked). Only the final column j=VL
// is captured: B[i][VL] = D[i][VL] - IDC*(i+VL); the uniform -IDC*VL term is
// folded after the per-table argmax (doesn't change argmax over i).
// fb = lane's base into the pair tile; q0..q2 are SGPR-resident packed ids.
template<int VL>
__device__ __forceinline__ unsigned long long dp_one(
    const float* __restrict__ fb,
    unsigned q0, unsigned q1, unsigned q2,
    const float* cvec, int lbase, int vid)
{
  float D[MAXVL_ + 1];
#pragma unroll
  for (int i = 0; i <= MAXVL_; ++i) D[i] = 0.f;

#pragma unroll
  for (int j = 0; j < VL; ++j) {
    unsigned qq = (j < 4) ? q0 : ((j < 8) ? q1 : q2);
    int k2 = (int)((qq >> ((j & 3) * 8)) & 0xFFu) * 2;   // dword offset (scalar)
    // 5 aligned ds_read_b64, row offsets fold into offset immediates
    float2 p0 = *(const float2*)(fb + k2);
    float2 p1 = *(const float2*)(fb + k2 + S2_);
    float2 p2 = *(const float2*)(fb + k2 + 2 * S2_);
    float2 p3 = *(const float2*)(fb + k2 + 3 * S2_);
    float2 p4 = *(const float2*)(fb + k2 + 4 * S2_);
    float s[MAXVL_] = {p0.x, p1.x, p2.x, p3.x, p4.x,
                       p0.y, p1.y, p2.y, p3.y, p4.y};
    float left = 0.f;
#pragma unroll
    for (int i = 1; i <= MAXVL_; ++i) {
      float nv = fmaxf(D[i - 1] + s[i - 1], fmaxf(D[i], left));  // add + max3
      D[i - 1] = left;          // delayed write-back (old D[i-1] consumed)
      left = nv;
    }
    D[MAXVL_] = left;
  }

  float bestSc = -1e30f;
  int bestEV = 0;
#pragma unroll
  for (int e = 0; e < NE_; ++e) {
    float sc = D[MIN_WL_ + e] + cvec[e];     // cvec masks non-viable (i,lane)
    if (sc > bestSc) { bestSc = sc; bestEV = e * V_; }  // strict >: smallest e
  }
  bestSc -= IDC_ * (float)VL;
  unsigned idx = (unsigned)(lbase + bestEV + vid);
  unsigned u = __float_as_uint(bestSc);
  u = (u & 0x80000000u) ? ~u : (u | 0x80000000u);
  unsigned long long key =
      ((unsigned long long)u << 32) | (unsigned long long)(~idx);
  return (bestSc > -1e29f) ? key : 0ull;
}

// -------------------------------------------------------------------------
// Kernel 2: DP, lane = position, vocab wave-uniform. Grid (B, 50) x 256;
// each block stages its b's tile once and runs 40 vocabs (10 per wave).
// Vocab ids live in SGPRs (readfirstlane), vlen dispatch is a scalar branch,
// LDS reads are conflict-free min-cycle ds_read_b64 (see S2_ comment).
__global__ __launch_bounds__(256) void dp_kernel(
    const int* __restrict__ lengths,
    const float* __restrict__ ws_plp,       // (B*L, KU), pre-shifted by +2*IDC
    const int* __restrict__ vpack,          // (V, int4)
    unsigned long long* __restrict__ g_best)
{
  __shared__ float sp[NKEY_ * S2_];        // 43,632 B
  __shared__ unsigned long long swave[4];
  int b = blockIdx.x;
  int chunk = blockIdx.y;
  int t = threadIdx.x;
  int len_b = lengths[b];

  // stage pair tile: sp[key][k] = {plp[b*L+key][k], plp[b*L+key+5][k]}
  // (rows beyond this b are garbage-but-masked; clamp keeps reads in-bounds)
  const float4* src4 = (const float4*)ws_plp;
  for (int idx = t; idx < NKEY_ * 25; idx += 256) {
    int key = idx / 25, m = idx - key * 25;
    int ra = b * L_ + key;     if (ra > B_ * L_ - 1) ra = B_ * L_ - 1;
    int rb = b * L_ + key + 5; if (rb > B_ * L_ - 1) rb = B_ * L_ - 1;
    float4 qa = src4[ra * 25 + m];
    float4 qb = src4[rb * 25 + m];
    float2* dst = (float2*)&sp[key * S2_ + 8 * m];
    dst[0] = make_float2(qa.x, qb.x);
    dst[1] = make_float2(qa.y, qb.y);
    dst[2] = make_float2(qa.z, qb.z);
    dst[3] = make_float2(qa.w, qb.w);
  }

  int lane = t & 63, w = t >> 6;
  // per-lane capture constants, pre-masked (viable <=> lane<L && i<=len-lane)
  float cvec[NE_];
#pragma unroll
  for (int e = 0; e < NE_; ++e) {
    int i = MIN_WL_ + e;
    bool ok = (lane < L_) && (i <= len_b - lane);
    cvec[e] = ok ? ((float)(len_b - i) * LOG_UNEXT_ - IDC_ * (float)i) : -1e30f;
  }
  int lbase = lane * (NE_ * V_);
  int lcl = (lane < L_) ? lane : (L_ - 1);   // keep masked lanes in-bounds
  const float* fb = sp + lcl * S2_;
  __syncthreads();

  unsigned long long bestKey = 0ull;
  const int4* vp4 = (const int4*)vpack;
#pragma unroll 1
  for (int n = 0; n < 10; ++n) {
    int v = chunk * 40 + w * 10 + n;
    int4 wq = vp4[v];                        // wave-uniform broadcast load
    unsigned q0 = (unsigned)__builtin_amdgcn_readfirstlane(wq.x);
    unsigned q1 = (unsigned)__builtin_amdgcn_readfirstlane(wq.y);
    unsigned q2 = (unsigned)__builtin_amdgcn_readfirstlane(wq.z);
    unsigned q3 = (unsigned)__builtin_amdgcn_readfirstlane(wq.w);
    int vlen = (int)(q3 & 0xFFu);
    int vid = (int)(q3 >> 8);
    unsigned long long kk = 0ull;
    switch (vlen) {                          // uniform scalar branch
      case 4:  kk = dp_one<4>(fb, q0, q1, q2, cvec, lbase, vid); break;
      case 5:  kk = dp_one<5>(fb, q0, q1, q2, cvec, lbase, vid); break;
      case 6:  kk = dp_one<6>(fb, q0, q1, q2, cvec, lbase, vid); break;
      case 7:  kk = dp_one<7>(fb, q0, q1, q2, cvec, lbase, vid); break;
      case 8:  kk = dp_one<8>(fb, q0, q1, q2, cvec, lbase, vid); break;
      case 9:  kk = dp_one<9>(fb, q0, q1, q2, cvec, lbase, vid); break;
      case 10: kk = dp_one<10>(fb, q0, q1, q2, cvec, lbase, vid); break;
      default: break;
    }
    if (kk > bestKey) bestKey = kk;
  }

#pragma unroll
  for (int off = 32; off > 0; off >>= 1) {
    unsigned long long o = __shfl_down(bestKey, off);
    if (o > bestKey) bestKey = o;
  }
  if ((t & 63) == 0) swave[w] = bestKey;
  __syncthreads();
  if (t == 0) {
    unsigned long long k0 = swave[0];
    for (int x = 1; x < 4; ++x)
      if (swave[x] > k0) k0 = swave[x];
    atomicMax(g_best + (size_t)b * BEST_STRIDE, k0);
  }
}

// -------------------------------------------------------------------------
// Kernel 3: decode. Separate launch = implicit device-wide fence (cheap).
__global__ void decode_kernel(const unsigned long long* __restrict__ g_best,
                              float* __restrict__ out)
{
  int t = threadIdx.x;
  if (t < B_) {
    unsigned long long key = g_best[t * BEST_STRIDE];
    unsigned int u = (unsigned int)(key >> 32);
    unsigned int idx = ~((unsigned int)(key & 0xFFFFFFFFull));
    unsigned int bits = (u & 0x80000000u) ? (u & 0x7FFFFFFFu) : ~u;
    float val = __uint_as_float(bits);
    int start = (int)(idx / (NE_ * V_));
    int rem = (int)(idx % (NE_ * V_));
    int e = rem / V_;
    int vv = rem % V_;
    out[t] = (float)start;
    out[B_ + t] = (float)(start + MIN_WL_ + e - 1);
    out[2 * B_ + t] = val;
    out[3 * B_ + t] = (float)vv;
  }
}

// -------------------------------------------------------------------------
extern "C" void kernel_launch(void* const* d_in, const int* in_sizes, int n_in,
                              void* d_out, int out_size, void* d_ws, size_t ws_size,
                              hipStream_t stream)
{
  const int* uid            = (const int*)d_in[0];
  const int* lengths        = (const int*)d_in[1];
  const float* unit_repr    = (const float*)d_in[2];
  const float* aligner_w    = (const float*)d_in[3];
  const float* conv_w       = (const float*)d_in[4];
  const float* conv_b       = (const float*)d_in[5];
  const int* vocab_ids      = (const int*)d_in[6];
  const int* vocab_lengths  = (const int*)d_in[7];
  float* out = (float*)d_out;
  float* ws_f = (float*)d_ws;
  unsigned long long* g_best =
      (unsigned long long*)((char*)d_ws + WS_BEST_BYTES);
  int* vpack = (int*)((char*)d_ws + WS_VPACK_BYTES);

  ctx_kernel<<<B_ * NQ_ + 1, 256, 0, stream>>>(uid, unit_repr, aligner_w,
                                               conv_w, conv_b, vocab_ids,
                                               vocab_lengths, ws_f + WS_PLP,
                                               out + 4 * B_, g_best, vpack);
  dim3 g3(B_, 50);
  dp_kernel<<<g3, 256, 0, stream>>>(lengths, ws_f + WS_PLP, vpack, g_best);
  decode_kernel<<<1, 64, 0, stream>>>(g_best, out);
}

// Round 5
// 106.203 us; speedup vs baseline: 1.0021x; 1.0021x over previous
//
#include <hip/hip_runtime.h>
#include <math.h>
#include <stdint.h>

#define B_ 16
#define L_ 50
#define LU_ 60
#define KU_ 100
#define DIM_ 60
#define V_ 2000
#define MAXVL_ 10
#define MIN_WL_ 4
#define MAX_WL_ 10
#define NE_ 7            // MAX_WL - MIN_WL + 1
#define IDC_ 3.5f
#define LOG_UNEXT_ (-4.6051701859880913680359829093687f)  // log(0.01)
#define CTXW_ 0.1f
#define NQ_ 13           // l-quads per batch row (13*4 >= 50)

// workspace layout (bytes)
#define WS_PLP  0                  // pos_lp(+2*IDC): B*L*KU = 80000 floats
#define WS_BEST_BYTES (80000u * 4u)       // 320000: 16 padded u64 slots
#define BEST_STRIDE 8              // 64 B between per-batch atomic slots
#define WS_CNT_OFF   (WS_BEST_BYTES + 1024u)   // 16 u32 counters, 64B-strided
#define CNT_STRIDE 16              // dwords between per-b counters
#define WS_VPACK_BYTES (WS_BEST_BYTES + 2048u) // 2000 int4, 16B aligned

#define URP_ 61   // padded LDS stride (odd -> conflict-free strided reads)
#define CWP_ 61

// DP tile: pair rows (r, r+5) as float2, stride S2_ dwords.
// Lane-to-bank step = 202 mod 32 = 10 -> 64 lanes put exactly 4 dwords on
// each of the 32 banks per b64 read = minimum bank cycles (conflict-free).
#define S2_ 202
#define NKEY_ 54  // keys 0..53 (lane<=49, d<=4)

// -------------------------------------------------------------------------
// Kernel 1: fused prep+ctx (208 blocks) + vocab byte-pack (block 208).
// ws_plp stores pos_lp + 2*IDC (potential-transformed DP operand).
// Block 0 zeroes g_best and the 16 per-b completion counters.
__global__ __launch_bounds__(256) void ctx_kernel(
    const int* __restrict__ uid,        // (B, L)
    const float* __restrict__ unit_repr,// (KU, DIM)
    const float* __restrict__ aligner_w,// (LU, KU)
    const float* __restrict__ conv_w,   // (DIM, DIM, 3)
    const float* __restrict__ conv_b,   // (DIM,)
    const int* __restrict__ vocab_ids,  // (V, MAXVL)
    const int* __restrict__ vocab_lengths, // (V,)
    float* __restrict__ ws_plp,         // (B*L, KU)
    float* __restrict__ out_align,      // (LU, KU)
    unsigned long long* __restrict__ g_best,
    unsigned* __restrict__ cnt,
    int* __restrict__ vpack)            // (V, int4)
{
  int blk = blockIdx.x;
  int t = threadIdx.x;

  // ---- pack block: vpack[v] = {3 byte-packed id dwords, vlen | v<<8}
  if (blk == B_ * NQ_) {
    for (int v = t; v < V_; v += 256) {
      int vl = vocab_lengths[v];
      unsigned q0 = 0u, q1 = 0u, q2 = 0u;
#pragma unroll
      for (int j = 0; j < 4; ++j) q0 |= ((unsigned)vocab_ids[v * MAXVL_ + j]) << (j * 8);
#pragma unroll
      for (int j = 0; j < 4; ++j) q1 |= ((unsigned)vocab_ids[v * MAXVL_ + 4 + j]) << (j * 8);
#pragma unroll
      for (int j = 0; j < 2; ++j) q2 |= ((unsigned)vocab_ids[v * MAXVL_ + 8 + j]) << (j * 8);
      int4 w;
      w.x = (int)q0; w.y = (int)q1; w.z = (int)q2;
      w.w = (int)((unsigned)vl | ((unsigned)v << 8));
      ((int4*)vpack)[v] = w;
    }
    return;
  }

  int b = blk / NQ_, q = blk % NQ_;
  int l0 = 4 * q;
  int npos = (l0 + 4 <= L_) ? 4 : (L_ - l0);
  int alr = (blk < LU_) ? blk : -1;

  __shared__ float s_ur[KU_ * URP_];       // unit_repr padded (6100)
  __shared__ float s_cw[3 * DIM_ * CWP_];  // conv_w transposed (10980)
  __shared__ float s_aw[7 * KU_];          // 6 neighborhood aligner rows + align row
  __shared__ float s_kx[7 * DIM_];         // 6 ku rows + align ku row
  __shared__ float swr[4 * DIM_];          // conv outputs
  __shared__ float sclp[4 * KU_];          // char logits per position
  __shared__ float sctx[4 * KU_];          // ctx logits per position
  __shared__ float salg[KU_];              // align logits
  __shared__ float sls[9];                 // 8 pos logsumexps + align

  if (blk == 0) {
    if (t < B_) g_best[t * BEST_STRIDE] = 0ull;
    if (t >= 32 && t < 32 + B_) cnt[(t - 32) * CNT_STRIDE] = 0u;
  }

  // --- P0: stage weights (float4 global) + aligner rows
  const float4* ur4 = (const float4*)unit_repr;
  for (int k = t; k < (KU_ * DIM_) / 4; k += 256) {
    float4 v = ur4[k];
    int i0 = 4 * k;
    s_ur[((i0 + 0) / DIM_) * URP_ + ((i0 + 0) % DIM_)] = v.x;
    s_ur[((i0 + 1) / DIM_) * URP_ + ((i0 + 1) % DIM_)] = v.y;
    s_ur[((i0 + 2) / DIM_) * URP_ + ((i0 + 2) % DIM_)] = v.z;
    s_ur[((i0 + 3) / DIM_) * URP_ + ((i0 + 3) % DIM_)] = v.w;
  }
  const float4* cw4 = (const float4*)conv_w;
  for (int k = t; k < (DIM_ * DIM_ * 3) / 4; k += 256) {
    float4 v = cw4[k];
    int i0 = 4 * k;
    float vv[4] = {v.x, v.y, v.z, v.w};
#pragma unroll
    for (int e = 0; e < 4; ++e) {
      int idx = i0 + e;
      int o = idx / (3 * DIM_), id = idx % (3 * DIM_);
      s_cw[id * CWP_ + o] = vv[e];
    }
  }
  for (int i = t; i < 7 * KU_; i += 256) {
    int m = i / KU_, k = i - m * KU_;
    float w = 0.f;
    if (m < 6) {
      int ld = l0 - 1 + m;
      if (ld >= 0 && ld < L_) {
        int u = uid[b * L_ + ld];
        w = aligner_w[u * KU_ + k];
      }
    } else if (alr >= 0) {
      w = aligner_w[alr * KU_ + k];
    }
    s_aw[i] = w;
  }
  __syncthreads();

  // --- P1: ku rows (420 outputs, 100 MACs)
  for (int idx = t; idx < 7 * DIM_; idx += 256) {
    int m = idx / DIM_, c = idx - m * DIM_;
    const float4* aw4 = (const float4*)&s_aw[m * KU_];
    float acc = 0.f;
    for (int k4 = 0; k4 < KU_ / 4; ++k4) {
      float4 a = aw4[k4];
      int k = 4 * k4;
      acc += a.x * s_ur[(k + 0) * URP_ + c];
      acc += a.y * s_ur[(k + 1) * URP_ + c];
      acc += a.z * s_ur[(k + 2) * URP_ + c];
      acc += a.w * s_ur[(k + 3) * URP_ + c];
    }
    s_kx[idx] = acc;
  }
  __syncthreads();

  // --- P2: conv (240) + char logits (400)
  for (int idx = t; idx < 240 + 4 * KU_; idx += 256) {
    if (idx < 240) {
      int p = idx / DIM_, o = idx - p * DIM_;
      const float4* x04 = (const float4*)&s_kx[(p + 0) * DIM_];
      const float4* x14 = (const float4*)&s_kx[(p + 1) * DIM_];
      const float4* x24 = (const float4*)&s_kx[(p + 2) * DIM_];
      float acc = conv_b[o];
      for (int i4 = 0; i4 < DIM_ / 4; ++i4) {
        float4 x0 = x04[i4], x1 = x14[i4], x2 = x24[i4];
        int i = 4 * i4;
        acc += x0.x * s_cw[((i + 0) * 3 + 0) * CWP_ + o];
        acc += x1.x * s_cw[((i + 0) * 3 + 1) * CWP_ + o];
        acc += x2.x * s_cw[((i + 0) * 3 + 2) * CWP_ + o];
        acc += x0.y * s_cw[((i + 1) * 3 + 0) * CWP_ + o];
        acc += x1.y * s_cw[((i + 1) * 3 + 1) * CWP_ + o];
        acc += x2.y * s_cw[((i + 1) * 3 + 2) * CWP_ + o];
        acc += x0.z * s_cw[((i + 2) * 3 + 0) * CWP_ + o];
        acc += x1.z * s_cw[((i + 2) * 3 + 1) * CWP_ + o];
        acc += x2.z * s_cw[((i + 2) * 3 + 2) * CWP_ + o];
        acc += x0.w * s_cw[((i + 3) * 3 + 0) * CWP_ + o];
        acc += x1.w * s_cw[((i + 3) * 3 + 1) * CWP_ + o];
        acc += x2.w * s_cw[((i + 3) * 3 + 2) * CWP_ + o];
      }
      swr[p * DIM_ + o] = acc;
    } else {
      int r = idx - 240;
      int p = r / KU_, j = r - p * KU_;
      const float4* kx4 = (const float4*)&s_kx[(p + 1) * DIM_];
      float acc = 0.f;
      for (int d4 = 0; d4 < DIM_ / 4; ++d4) {
        float4 x = kx4[d4];
        int d = 4 * d4;
        acc += x.x * s_ur[j * URP_ + d + 0];
        acc += x.y * s_ur[j * URP_ + d + 1];
        acc += x.z * s_ur[j * URP_ + d + 2];
        acc += x.w * s_ur[j * URP_ + d + 3];
      }
      sclp[r] = acc;
    }
  }
  __syncthreads();

  // --- P3: ctx logits (400) + align logits (100)
  for (int idx = t; idx < 4 * KU_ + KU_; idx += 256) {
    if (idx < 4 * KU_) {
      int p = idx / KU_, j = idx - p * KU_;
      const float4* w4 = (const float4*)&swr[p * DIM_];
      float acc = 0.f;
      for (int d4 = 0; d4 < DIM_ / 4; ++d4) {
        float4 x = w4[d4];
        int d = 4 * d4;
        acc += x.x * s_ur[j * URP_ + d + 0];
        acc += x.y * s_ur[j * URP_ + d + 1];
        acc += x.z * s_ur[j * URP_ + d + 2];
        acc += x.w * s_ur[j * URP_ + d + 3];
      }
      sctx[idx] = acc;
    } else {
      int j = idx - 4 * KU_;
      const float4* kx4 = (const float4*)&s_kx[6 * DIM_];
      float acc = 0.f;
      for (int d4 = 0; d4 < DIM_ / 4; ++d4) {
        float4 x = kx4[d4];
        int d = 4 * d4;
        acc += x.x * s_ur[j * URP_ + d + 0];
        acc += x.y * s_ur[j * URP_ + d + 1];
        acc += x.z * s_ur[j * URP_ + d + 2];
        acc += x.w * s_ur[j * URP_ + d + 3];
      }
      salg[j] = acc;
    }
  }
  __syncthreads();

  // --- P4: 9 logsumexp reductions
  {
    int g = t >> 5, lane = t & 31;
#pragma unroll
    for (int round = 0; round < 2; ++round) {
      int r = round * 8 + g;
      if (r < 9) {
        const float* arr = (r == 8) ? salg
                          : ((r & 1) ? &sctx[(r >> 1) * KU_] : &sclp[(r >> 1) * KU_]);
        float v1 = arr[lane];
        float v2 = arr[32 + lane];
        float v3 = arr[64 + lane];
        float v4 = (lane < KU_ - 96) ? arr[96 + lane] : -1e30f;
        float mx = fmaxf(fmaxf(v1, v2), fmaxf(v3, v4));
#pragma unroll
        for (int off = 16; off > 0; off >>= 1)
          mx = fmaxf(mx, __shfl_xor(mx, off));
        float s = expf(v1 - mx) + expf(v2 - mx) + expf(v3 - mx) +
                  ((lane < KU_ - 96) ? expf(v4 - mx) : 0.f);
#pragma unroll
        for (int off = 16; off > 0; off >>= 1)
          s += __shfl_xor(s, off);
        if (lane == 0) sls[r] = mx + logf(s);
      }
    }
  }
  __syncthreads();

  // --- P5: guarded outputs (pos_lp + 2*IDC: DP potential-transform operand)
  for (int idx = t; idx < 4 * KU_; idx += 256) {
    int p = idx / KU_, j = idx - p * KU_;
    if (p < npos) {
      float pos = (sclp[idx] - sls[2 * p]) + CTXW_ * (sctx[idx] - sls[2 * p + 1]);
      ws_plp[(b * L_ + l0 + p) * KU_ + j] = pos + 2.0f * IDC_;
    }
  }
  if (alr >= 0 && t < KU_)
    out_align[alr * KU_ + t] = expf(salg[t] - sls[8]);
}

// -------------------------------------------------------------------------
// DP core for one wave-uniform vocab of length VL (see round-4 notes).
template<int VL>
__device__ __forceinline__ unsigned long long dp_one(
    const float* __restrict__ fb,
    unsigned q0, unsigned q1, unsigned q2,
    const float* cvec, int lbase, int vid)
{
  float D[MAXVL_ + 1];
#pragma unroll
  for (int i = 0; i <= MAXVL_; ++i) D[i] = 0.f;

#pragma unroll
  for (int j = 0; j < VL; ++j) {
    unsigned qq = (j < 4) ? q0 : ((j < 8) ? q1 : q2);
    int k2 = (int)((qq >> ((j & 3) * 8)) & 0xFFu) * 2;   // dword offset (scalar)
    // 5 aligned ds_read_b64, row offsets fold into offset immediates
    float2 p0 = *(const float2*)(fb + k2);
    float2 p1 = *(const float2*)(fb + k2 + S2_);
    float2 p2 = *(const float2*)(fb + k2 + 2 * S2_);
    float2 p3 = *(const float2*)(fb + k2 + 3 * S2_);
    float2 p4 = *(const float2*)(fb + k2 + 4 * S2_);
    float s[MAXVL_] = {p0.x, p1.x, p2.x, p3.x, p4.x,
                       p0.y, p1.y, p2.y, p3.y, p4.y};
    float left = 0.f;
#pragma unroll
    for (int i = 1; i <= MAXVL_; ++i) {
      float nv = fmaxf(D[i - 1] + s[i - 1], fmaxf(D[i], left));  // add + max3
      D[i - 1] = left;          // delayed write-back (old D[i-1] consumed)
      left = nv;
    }
    D[MAXVL_] = left;
  }

  float bestSc = -1e30f;
  int bestEV = 0;
#pragma unroll
  for (int e = 0; e < NE_; ++e) {
    float sc = D[MIN_WL_ + e] + cvec[e];     // cvec masks non-viable (i,lane)
    if (sc > bestSc) { bestSc = sc; bestEV = e * V_; }  // strict >: smallest e
  }
  bestSc -= IDC_ * (float)VL;
  unsigned idx = (unsigned)(lbase + bestEV + vid);
  unsigned u = __float_as_uint(bestSc);
  u = (u & 0x80000000u) ? ~u : (u | 0x80000000u);
  unsigned long long key =
      ((unsigned long long)u << 32) | (unsigned long long)(~idx);
  return (bestSc > -1e29f) ? key : 0ull;
}

// -------------------------------------------------------------------------
// Kernel 2: DP, lane = position, vocab wave-uniform. Grid (B, 50) x 256.
// NEW vs round 4: (a) vpack loads are software-pipelined (prefetch wq_next
// before consuming wq -> the per-iteration s_waitcnt is counted, not
// vmcnt(0); removes ~10x200-400cyc serial L2 latency per wave);
// (b) decode fused via per-b completion counters (50 arrivals each, own
// 64B line -> sub-us tail; r1's regression was ONE counter x 1600 blocks).
// Ordering: block-best atomicMax return is consumed before the counter
// atomicAdd; the 50th block re-reads g_best[b] via atomic RMW (coherence
// point) and writes the decoded outputs for its b.
__global__ __launch_bounds__(256) void dp_kernel(
    const int* __restrict__ lengths,
    const float* __restrict__ ws_plp,       // (B*L, KU), pre-shifted by +2*IDC
    const int* __restrict__ vpack,          // (V, int4)
    unsigned long long* __restrict__ g_best,
    unsigned* __restrict__ cnt,
    float* __restrict__ out)
{
  __shared__ float sp[NKEY_ * S2_];        // 43,632 B
  __shared__ unsigned long long swave[4];
  int b = blockIdx.x;
  int chunk = blockIdx.y;
  int t = threadIdx.x;
  int len_b = lengths[b];

  // stage pair tile: sp[key][k] = {plp[b*L+key][k], plp[b*L+key+5][k]}
  const float4* src4 = (const float4*)ws_plp;
  for (int idx = t; idx < NKEY_ * 25; idx += 256) {
    int key = idx / 25, m = idx - key * 25;
    int ra = b * L_ + key;     if (ra > B_ * L_ - 1) ra = B_ * L_ - 1;
    int rb = b * L_ + key + 5; if (rb > B_ * L_ - 1) rb = B_ * L_ - 1;
    float4 qa = src4[ra * 25 + m];
    float4 qb = src4[rb * 25 + m];
    float2* dst = (float2*)&sp[key * S2_ + 8 * m];
    dst[0] = make_float2(qa.x, qb.x);
    dst[1] = make_float2(qa.y, qb.y);
    dst[2] = make_float2(qa.z, qb.z);
    dst[3] = make_float2(qa.w, qb.w);
  }

  int lane = t & 63, w = t >> 6;
  // per-lane capture constants, pre-masked (viable <=> lane<L && i<=len-lane)
  float cvec[NE_];
#pragma unroll
  for (int e = 0; e < NE_; ++e) {
    int i = MIN_WL_ + e;
    bool ok = (lane < L_) && (i <= len_b - lane);
    cvec[e] = ok ? ((float)(len_b - i) * LOG_UNEXT_ - IDC_ * (float)i) : -1e30f;
  }
  int lbase = lane * (NE_ * V_);
  int lcl = (lane < L_) ? lane : (L_ - 1);   // keep masked lanes in-bounds
  const float* fb = sp + lcl * S2_;
  __syncthreads();

  unsigned long long bestKey = 0ull;
  const int4* vp4 = (const int4*)vpack;
  int vbase = chunk * 40 + w * 10;
  int4 wq = vp4[vbase];                      // head of the pipeline
#pragma unroll 1
  for (int n = 0; n < 10; ++n) {
    // prefetch next entry BEFORE consuming wq: its load flies under dp_one
    int4 wqn = vp4[vbase + ((n < 9) ? (n + 1) : 9)];
    unsigned q0 = (unsigned)__builtin_amdgcn_readfirstlane(wq.x);
    unsigned q1 = (unsigned)__builtin_amdgcn_readfirstlane(wq.y);
    unsigned q2 = (unsigned)__builtin_amdgcn_readfirstlane(wq.z);
    unsigned q3 = (unsigned)__builtin_amdgcn_readfirstlane(wq.w);
    int vlen = (int)(q3 & 0xFFu);
    int vid = (int)(q3 >> 8);
    unsigned long long kk = 0ull;
    switch (vlen) {                          // uniform scalar branch
      case 4:  kk = dp_one<4>(fb, q0, q1, q2, cvec, lbase, vid); break;
      case 5:  kk = dp_one<5>(fb, q0, q1, q2, cvec, lbase, vid); break;
      case 6:  kk = dp_one<6>(fb, q0, q1, q2, cvec, lbase, vid); break;
      case 7:  kk = dp_one<7>(fb, q0, q1, q2, cvec, lbase, vid); break;
      case 8:  kk = dp_one<8>(fb, q0, q1, q2, cvec, lbase, vid); break;
      case 9:  kk = dp_one<9>(fb, q0, q1, q2, cvec, lbase, vid); break;
      case 10: kk = dp_one<10>(fb, q0, q1, q2, cvec, lbase, vid); break;
      default: break;
    }
    if (kk > bestKey) bestKey = kk;
    wq = wqn;
  }

#pragma unroll
  for (int off = 32; off > 0; off >>= 1) {
    unsigned long long o = __shfl_down(bestKey, off);
    if (o > bestKey) bestKey = o;
  }
  if ((t & 63) == 0) swave[w] = bestKey;
  __syncthreads();
  if (t == 0) {
    unsigned long long k0 = swave[0];
    for (int x = 1; x < 4; ++x)
      if (swave[x] > k0) k0 = swave[x];
    unsigned long long old = atomicMax(g_best + (size_t)b * BEST_STRIDE, k0);
    asm volatile("" :: "v"(old));   // consume: RMW complete before counter bump
    unsigned prev = atomicAdd(&cnt[b * CNT_STRIDE], 1u);
    if (prev == (unsigned)(L_ - 1)) {
      // last of the 50 blocks for this b: decode (read at coherence point)
      unsigned long long key = atomicMax(g_best + (size_t)b * BEST_STRIDE, 0ull);
      unsigned int u = (unsigned int)(key >> 32);
      unsigned int idx = ~((unsigned int)(key & 0xFFFFFFFFull));
      unsigned int bits = (u & 0x80000000u) ? (u & 0x7FFFFFFFu) : ~u;
      float val = __uint_as_float(bits);
      int start = (int)(idx / (NE_ * V_));
      int rem = (int)(idx % (NE_ * V_));
      int e = rem / V_;
      int vv = rem % V_;
      out[b] = (float)start;
      out[B_ + b] = (float)(start + MIN_WL_ + e - 1);
      out[2 * B_ + b] = val;
      out[3 * B_ + b] = (float)vv;
    }
  }
}

// -------------------------------------------------------------------------
extern "C" void kernel_launch(void* const* d_in, const int* in_sizes, int n_in,
                              void* d_out, int out_size, void* d_ws, size_t ws_size,
                              hipStream_t stream)
{
  const int* uid            = (const int*)d_in[0];
  const int* lengths        = (const int*)d_in[1];
  const float* unit_repr    = (const float*)d_in[2];
  const float* aligner_w    = (const float*)d_in[3];
  const float* conv_w       = (const float*)d_in[4];
  const float* conv_b       = (const float*)d_in[5];
  const int* vocab_ids      = (const int*)d_in[6];
  const int* vocab_lengths  = (const int*)d_in[7];
  float* out = (float*)d_out;
  float* ws_f = (float*)d_ws;
  unsigned long long* g_best =
      (unsigned long long*)((char*)d_ws + WS_BEST_BYTES);
  unsigned* cnt = (unsigned*)((char*)d_ws + WS_CNT_OFF);
  int* vpack = (int*)((char*)d_ws + WS_VPACK_BYTES);

  ctx_kernel<<<B_ * NQ_ + 1, 256, 0, stream>>>(uid, unit_repr, aligner_w,
                                               conv_w, conv_b, vocab_ids,
                                               vocab_lengths, ws_f + WS_PLP,
                                               out + 4 * B_, g_best, cnt, vpack);
  dim3 g3(B_, 50);
  dp_kernel<<<g3, 256, 0, stream>>>(lengths, ws_f + WS_PLP, vpack, g_best,
                                    cnt, out);
}